// Round 2
// baseline (41809.583 us; speedup 1.0000x reference)
//
#include <hip/hip_runtime.h>
#include <stdint.h>

// ---------------------------------------------------------------------------
// TopDownLSTM: T=256, B=64, I=512, H=1024, L=3.
// Persistent-kernel design: 256 blocks (1/CU) x 512 threads (8 waves).
// Block b owns h-cols [4b,4b+4) => z-cols {g*1024 + 4b + j} for all 3 cells.
// 3 grid-barrier phases per timestep (cell0, cell1, cell2).
// Weights packed to bf16 MFMA-fragment layout once per call.
// ---------------------------------------------------------------------------

using bf16x8 = __attribute__((ext_vector_type(8))) short;   // 8 bf16 (4 VGPRs)
using f32x4  = __attribute__((ext_vector_type(4))) float;   // MFMA acc

#define DEVINL __device__ __forceinline__

constexpr int T_ = 256, B_ = 64, I_ = 512, H_ = 1024;

// Workspace layout (bytes). Total ~80.9 MB.
constexpr size_t PIECE_ELEMS = 256ull * 1024 * 16;            // K=1024 packed piece (ushort elems)
constexpr size_t WP7_ELEMS   = 256ull * 512 * 16;             // K=512 x-piece
constexpr size_t WP_TOTAL    = 7 * PIECE_ELEMS + WP7_ELEMS;   // 31,457,280 elems
constexpr size_t XB_OFF_B    = WP_TOTAL * 2;                  // 62,914,560
constexpr size_t HB_OFF_B    = XB_OFF_B + 256ull * 64 * 512 * 2;   // 79,691,776
constexpr size_t SYNC_OFF_B  = HB_OFF_B + 2ull * 3 * 64 * 1024 * 2; // 80,478,208 (dbuf h mirror)
constexpr size_t SYNC_BYTES  = 769ull * 128 * 4;              // 769 barriers x 8 groups x 64B

DEVINL ushort f2bf(float f) {                     // fp32 -> bf16 RNE
  uint32_t x = __float_as_uint(f);
  uint32_t r = (x + 0x7fffu + ((x >> 16) & 1u)) >> 16;
  return (ushort)r;
}
DEVINL float sigf(float x) { return 1.0f / (1.0f + __expf(-x)); }
DEVINL float tanhf_(float x) {                    // overflow-safe tanh
  float ax = fabsf(x);
  float e  = __expf(-2.0f * ax);
  float t  = (1.0f - e) / (1.0f + e);
  return copysignf(t, x);
}

// ---------------------------------------------------------------------------
// Pack one weight matrix W[K][4096] (fp32) into per-block B-fragment layout:
//   dst[b][kb][c][i] = bf16( W[kb*8+i][ (c>>2)*1024 + 4*b + (c&3) ] )
// so a lane (n=c, q) reads 8 contiguous bf16 = one MFMA B-fragment quarter.
// grid = 256 blocks (b), 256 threads.
// ---------------------------------------------------------------------------
__global__ void pack_w(const float* __restrict__ src, ushort* __restrict__ dst, int K) {
  __shared__ ushort tile[1024 * 16];              // [k][c], 32 KB max
  const int b = blockIdx.x, tid = threadIdx.x;
  for (int idx = tid; idx < K * 4; idx += 256) {
    int k = idx >> 2, g = idx & 3;
    float4 v = *reinterpret_cast<const float4*>(src + (size_t)k * 4096 + g * 1024 + 4 * b);
    ushort* tp = &tile[k * 16 + g * 4];
    tp[0] = f2bf(v.x); tp[1] = f2bf(v.y); tp[2] = f2bf(v.z); tp[3] = f2bf(v.w);
  }
  __syncthreads();
  ushort* db = dst + (size_t)b * K * 16;
  for (int o8 = tid; o8 < K * 2; o8 += 256) {     // K*16/8 vector-stores
    int kb = o8 >> 4, c = o8 & 15;
    bf16x8 val;
#pragma unroll
    for (int i = 0; i < 8; ++i) val[i] = (short)tile[(kb * 8 + i) * 16 + c];
    *reinterpret_cast<bf16x8*>(db + o8 * 8) = val;  // coalesced
  }
}

// x fp32 -> bf16 (whole [T][64][512] tensor). grid 8192 x 256, exact.
__global__ void cvt_x(const float* __restrict__ x, ushort* __restrict__ xb) {
  int i = blockIdx.x * blockDim.x + threadIdx.x;
  float4 v = reinterpret_cast<const float4*>(x)[i];
  ushort4 u;
  u.x = f2bf(v.x); u.y = f2bf(v.y); u.z = f2bf(v.z); u.w = f2bf(v.w);
  reinterpret_cast<ushort4*>(xb)[i] = u;
}

// ---------------------------------------------------------------------------
// One GEMM piece: acc[64x16] += A[64xK] * Wpiece[Kx16], this wave's K/8 slice.
// A row-major bf16 (lda = 1024 or 512). Wp pre-packed as above.
// ---------------------------------------------------------------------------
template <int K, bool NT>
DEVINL void gemm_piece(f32x4 acc[4], const ushort* __restrict__ A, int lda,
                       const ushort* __restrict__ WpP, int b, int w, int r16, int q) {
  const int kw = (K / 8) * w;                     // wave's k-range start
  const ushort* wp = WpP + (size_t)b * (K * 16) + (size_t)q * 128 + r16 * 8;
  const ushort* ap = A + r16 * lda + q * 8;
#pragma unroll
  for (int ks = 0; ks < K / 256; ++ks) {
    const int k0 = kw + ks * 32;
    bf16x8 bf_;
    if constexpr (NT)
      bf_ = __builtin_nontemporal_load(reinterpret_cast<const bf16x8*>(wp + (size_t)(k0 >> 3) * 128));
    else
      bf_ = *reinterpret_cast<const bf16x8*>(wp + (size_t)(k0 >> 3) * 128);
    bf16x8 a0 = *reinterpret_cast<const bf16x8*>(ap + 0 * 16 * lda + k0);
    bf16x8 a1 = *reinterpret_cast<const bf16x8*>(ap + 1 * 16 * lda + k0);
    bf16x8 a2 = *reinterpret_cast<const bf16x8*>(ap + 2 * 16 * lda + k0);
    bf16x8 a3 = *reinterpret_cast<const bf16x8*>(ap + 3 * 16 * lda + k0);
    acc[0] = __builtin_amdgcn_mfma_f32_16x16x32_bf16(a0, bf_, acc[0], 0, 0, 0);
    acc[1] = __builtin_amdgcn_mfma_f32_16x16x32_bf16(a1, bf_, acc[1], 0, 0, 0);
    acc[2] = __builtin_amdgcn_mfma_f32_16x16x32_bf16(a2, bf_, acc[2], 0, 0, 0);
    acc[3] = __builtin_amdgcn_mfma_f32_16x16x32_bf16(a3, bf_, acc[3], 0, 0, 0);
  }
}

// Grid barrier: 8-group tree (group = bid&7, 32 blocks/group), fresh counter
// per instance (no reset races). Release fence drains+writes-back producer
// stores; acquire fence invalidates L1/L2 so consumers see fresh h.
DEVINL void grid_barrier(int* __restrict__ syncp, int bar) {
  __builtin_amdgcn_fence(__ATOMIC_RELEASE, "agent");
  __syncthreads();
  int* base = syncp + (size_t)bar * 128;          // 8 groups x 16 ints (64B apart)
  if (threadIdx.x == 0)
    __hip_atomic_fetch_add(base + (blockIdx.x & 7) * 16, 1,
                           __ATOMIC_RELAXED, __HIP_MEMORY_SCOPE_AGENT);
  if (threadIdx.x < 8) {
    while (__hip_atomic_load(base + threadIdx.x * 16,
                             __ATOMIC_RELAXED, __HIP_MEMORY_SCOPE_AGENT) < 32)
      __builtin_amdgcn_s_sleep(1);
  }
  __syncthreads();
  __builtin_amdgcn_fence(__ATOMIC_ACQUIRE, "agent");
}

// ---------------------------------------------------------------------------
// Persistent kernel.
// ---------------------------------------------------------------------------
__global__ void __launch_bounds__(512, 2)
lstm_persist(const ushort* __restrict__ Wp, const ushort* __restrict__ xb,
             ushort* __restrict__ Hb, int* __restrict__ syncp, float* __restrict__ outp,
             const float* __restrict__ h0, const float* __restrict__ c0,
             const int* __restrict__ len,
             const float* __restrict__ b0v, const float* __restrict__ b1v,
             const float* __restrict__ b2v) {
  const int b = blockIdx.x, tid = threadIdx.x;
  const int w = tid >> 6, lane = tid & 63, r16 = lane & 15, q = lane >> 4;
  __shared__ float zp[8 * 64 * 16];               // split-K partials, 32 KB

  const int gr = tid >> 2, gj = tid & 3;          // gate thread: row, col-within-4
  const int gcol = b * 4 + gj;

  int   mylen = 0;
  float h0r = 0, h1r = 0, h2r = 0, c0r = 0, c1r = 0, c2r = 0;

  if (tid < 256) {
    mylen = len[gr];
    h0r = h0[(0 * 64 + gr) * 1024 + gcol]; c0r = c0[(0 * 64 + gr) * 1024 + gcol];
    h1r = h0[(1 * 64 + gr) * 1024 + gcol]; c1r = c0[(1 * 64 + gr) * 1024 + gcol];
    h2r = h0[(2 * 64 + gr) * 1024 + gcol]; c2r = c0[(2 * 64 + gr) * 1024 + gcol];
    ushort* hbi = Hb + 3 * 64 * 1024;             // parity buffer 1 = "prev" for t=0
    hbi[(0 * 64 + gr) * 1024 + gcol] = f2bf(h0r);
    hbi[(1 * 64 + gr) * 1024 + gcol] = f2bf(h1r);
    hbi[(2 * 64 + gr) * 1024 + gcol] = f2bf(h2r);
  }
  grid_barrier(syncp, 0);

  const ushort* Wp0 = Wp + 0 * PIECE_ELEMS;       // Whh0   A=h0(prev)
  const ushort* Wp1 = Wp + 1 * PIECE_ELEMS;       // Wth0   A=h1(prev)
  const ushort* Wp2 = Wp + 2 * PIECE_ELEMS;       // Whh1   A=h1(prev)
  const ushort* Wp3 = Wp + 3 * PIECE_ELEMS;       // Wbh1   A=h0(cur)
  const ushort* Wp4 = Wp + 4 * PIECE_ELEMS;       // Wth1   A=h2(prev)
  const ushort* Wp5 = Wp + 5 * PIECE_ELEMS;       // Whh2   A=h2(prev)
  const ushort* Wp6 = Wp + 6 * PIECE_ELEMS;       // Wih2   A=h1(cur)
  const ushort* Wp7 = Wp + 7 * PIECE_ELEMS;       // Wbh0   A=x_t (K=512)

  // gates + masked state update + bf16 h-mirror write (+ optional output row)
  auto do_cell = [&](f32x4* acc, const float* bias, float& hr, float& cr,
                     ushort* hbw, int t, float* owrite) {
#pragma unroll
    for (int mf = 0; mf < 4; ++mf)
#pragma unroll
      for (int rg = 0; rg < 4; ++rg)
        zp[w * 1024 + (mf * 16 + q * 4 + rg) * 16 + r16] = acc[mf][rg];
    __syncthreads();
    if (tid < 256) {
      float z0 = 0, z1 = 0, z2 = 0, z3 = 0;
#pragma unroll
      for (int ww = 0; ww < 8; ++ww) {
        const float* zr = &zp[ww * 1024 + gr * 16];
        z0 += zr[0 * 4 + gj]; z1 += zr[1 * 4 + gj];
        z2 += zr[2 * 4 + gj]; z3 += zr[3 * 4 + gj];
      }
      z0 += bias[0 * 1024 + gcol]; z1 += bias[1 * 1024 + gcol];
      z2 += bias[2 * 1024 + gcol]; z3 += bias[3 * 1024 + gcol];
      float fg = sigf(z0), ig = sigf(z1), og = sigf(z2), gg = tanhf_(z3);
      float cn = fg * cr + ig * gg;
      float hn = og * tanhf_(cn);
      if (t < mylen) { cr = cn; hr = hn; }        // freeze when t >= length
      hbw[gr * 1024 + gcol] = f2bf(hr);
      if (owrite) owrite[gr * 1024 + gcol] = hr;
    }
    __syncthreads();                              // zp reused next phase
  };

  for (int t = 0; t < T_; ++t) {
    const int cur = t & 1, prv = cur ^ 1;
    ushort* HbC = Hb + (size_t)cur * 3 * 64 * 1024;
    const ushort* HbP = Hb + (size_t)prv * 3 * 64 * 1024;
    const ushort* hp0 = HbP;                 // h0(t-1)
    const ushort* hp1 = HbP + 65536;         // h1(t-1)
    const ushort* hp2 = HbP + 131072;        // h2(t-1)
    const ushort* hc0 = HbC;                 // h0(t)
    const ushort* hc1 = HbC + 65536;         // h1(t)

    { // ---- phase 0: cell 0 -------------------------------------------------
      f32x4 acc[4] = {{0,0,0,0},{0,0,0,0},{0,0,0,0},{0,0,0,0}};
      gemm_piece<1024, true>(acc, hp0, 1024, Wp0, b, w, r16, q);
      gemm_piece<1024, true>(acc, hp1, 1024, Wp1, b, w, r16, q);
      gemm_piece<512,  true>(acc, xb + (size_t)t * 64 * 512, 512, Wp7, b, w, r16, q);
      do_cell(acc, b0v, h0r, c0r, HbC + 0, t, nullptr);
      grid_barrier(syncp, 1 + t * 3 + 0);
    }
    { // ---- phase 1: cell 1 -------------------------------------------------
      f32x4 acc[4] = {{0,0,0,0},{0,0,0,0},{0,0,0,0},{0,0,0,0}};
      gemm_piece<1024, true>(acc, hp1, 1024, Wp2, b, w, r16, q);
      gemm_piece<1024, true>(acc, hc0, 1024, Wp3, b, w, r16, q);
      gemm_piece<1024, true>(acc, hp2, 1024, Wp4, b, w, r16, q);
      do_cell(acc, b1v, h1r, c1r, HbC + 65536, t, nullptr);
      grid_barrier(syncp, 1 + t * 3 + 1);
    }
    { // ---- phase 2: cell 2 -------------------------------------------------
      f32x4 acc[4] = {{0,0,0,0},{0,0,0,0},{0,0,0,0},{0,0,0,0}};
      gemm_piece<1024, true>(acc, hp2, 1024, Wp5, b, w, r16, q);
      gemm_piece<1024, true>(acc, hc1, 1024, Wp6, b, w, r16, q);
      do_cell(acc, b2v, h2r, c2r, HbC + 131072, t, outp + (size_t)t * 64 * 1024);
      grid_barrier(syncp, 1 + t * 3 + 2);
    }
  }

  if (tid < 256) {                                // final Ht, C (fp32 from regs)
    float* HtO = outp + (size_t)T_ * 64 * 1024;
    float* CO  = HtO + 3 * 64 * 1024;
    HtO[(0 * 64 + gr) * 1024 + gcol] = h0r;
    HtO[(1 * 64 + gr) * 1024 + gcol] = h1r;
    HtO[(2 * 64 + gr) * 1024 + gcol] = h2r;
    CO[(0 * 64 + gr) * 1024 + gcol] = c0r;
    CO[(1 * 64 + gr) * 1024 + gcol] = c1r;
    CO[(2 * 64 + gr) * 1024 + gcol] = c2r;
  }
}

// ---------------------------------------------------------------------------
extern "C" void kernel_launch(void* const* d_in, const int* in_sizes, int n_in,
                              void* d_out, int out_size, void* d_ws, size_t ws_size,
                              hipStream_t stream) {
  (void)in_sizes; (void)n_in; (void)out_size; (void)ws_size;
  const float* x    = (const float*)d_in[0];
  const int*   len  = (const int*)d_in[1];
  const float* h0   = (const float*)d_in[2];
  const float* c0   = (const float*)d_in[3];
  const float* Wbh0 = (const float*)d_in[4];
  const float* Whh0 = (const float*)d_in[5];
  const float* Wth0 = (const float*)d_in[6];
  const float* b0   = (const float*)d_in[7];
  const float* Wbh1 = (const float*)d_in[8];
  const float* Whh1 = (const float*)d_in[9];
  const float* Wth1 = (const float*)d_in[10];
  const float* b1   = (const float*)d_in[11];
  const float* Wih2 = (const float*)d_in[12];
  const float* Whh2 = (const float*)d_in[13];
  const float* b2   = (const float*)d_in[14];

  ushort* Wp    = (ushort*)d_ws;
  ushort* xb    = (ushort*)((char*)d_ws + XB_OFF_B);
  ushort* Hb    = (ushort*)((char*)d_ws + HB_OFF_B);
  int*    syncp = (int*)((char*)d_ws + SYNC_OFF_B);

  pack_w<<<256, 256, 0, stream>>>(Whh0, Wp + 0 * PIECE_ELEMS, 1024);
  pack_w<<<256, 256, 0, stream>>>(Wth0, Wp + 1 * PIECE_ELEMS, 1024);
  pack_w<<<256, 256, 0, stream>>>(Whh1, Wp + 2 * PIECE_ELEMS, 1024);
  pack_w<<<256, 256, 0, stream>>>(Wbh1, Wp + 3 * PIECE_ELEMS, 1024);
  pack_w<<<256, 256, 0, stream>>>(Wth1, Wp + 4 * PIECE_ELEMS, 1024);
  pack_w<<<256, 256, 0, stream>>>(Whh2, Wp + 5 * PIECE_ELEMS, 1024);
  pack_w<<<256, 256, 0, stream>>>(Wih2, Wp + 6 * PIECE_ELEMS, 1024);
  pack_w<<<256, 256, 0, stream>>>(Wbh0, Wp + 7 * PIECE_ELEMS, 512);
  cvt_x<<<8192, 256, 0, stream>>>(x, xb);
  (void)hipMemsetAsync(syncp, 0, SYNC_BYTES, stream);

  lstm_persist<<<256, 512, 0, stream>>>(Wp, xb, Hb, syncp, (float*)d_out,
                                        h0, c0, len, b0, b1, b2);
}

// Round 3
// 24065.359 us; speedup vs baseline: 1.7373x; 1.7373x over previous
//
#include <hip/hip_runtime.h>
#include <stdint.h>

// ---------------------------------------------------------------------------
// TopDownLSTM: T=256, B=64, I=512, H=1024, L=3.
// Persistent kernel: 128 blocks x 512 threads (8 waves). Block pb owns h-cols
// [8pb, 8pb+8) = packed column-groups b=2pb, 2pb+1. Two grid-barrier phases
// per timestep (skewed schedule):
//   phase A(t): cell0(t)  and  cell2(t-1)      [share h1(t-1) A-read]
//   phase B(t): cell1(t)
// h mirrors live in a 3-slot ring: slot(t) = t % 3 (producing timestep).
// Weights packed to bf16 MFMA-B-fragment layout once per call (one kernel).
// ---------------------------------------------------------------------------

using bf16x8 = __attribute__((ext_vector_type(8))) short;   // 8 bf16 (4 VGPRs)
using f32x4  = __attribute__((ext_vector_type(4))) float;   // MFMA acc

#define DEVINL __device__ __forceinline__

constexpr int T_ = 256;
constexpr int NBLK = 128;

// Workspace layout (bytes). Total ~81.4 MB.
constexpr size_t PIECE_ELEMS = 256ull * 1024 * 16;            // K=1024 packed piece
constexpr size_t WP7_ELEMS   = 256ull * 512 * 16;             // K=512 x-piece
constexpr size_t WP_TOTAL    = 7 * PIECE_ELEMS + WP7_ELEMS;   // 31,457,280 elems
constexpr size_t XB_OFF_B    = WP_TOTAL * 2;                  // 62,914,560
constexpr size_t HB_OFF_B    = XB_OFF_B + 256ull * 64 * 512 * 2;   // 79,691,776
constexpr size_t HSLOT       = 3ull * 64 * 1024;              // elems per ring slot
constexpr size_t SYNC_OFF_B  = HB_OFF_B + 3ull * HSLOT * 2;   // 80,871,424
constexpr size_t SYNC_BYTES  = 1024ull * 512;                 // 1024 barrier slots x 512B

DEVINL ushort f2bf(float f) {                     // fp32 -> bf16 RNE
  uint32_t x = __float_as_uint(f);
  uint32_t r = (x + 0x7fffu + ((x >> 16) & 1u)) >> 16;
  return (ushort)r;
}
DEVINL float sigf(float x) { return 1.0f / (1.0f + __expf(-x)); }
DEVINL float tanhf_(float x) {                    // overflow-safe tanh
  float ax = fabsf(x);
  float e  = __expf(-2.0f * ax);
  float t  = (1.0f - e) / (1.0f + e);
  return copysignf(t, x);
}

// ---------------------------------------------------------------------------
// Pack all 8 weight matrices W[K][4096] (fp32) into per-colgroup B-fragment
// layout: dst[piece][b][kb][c][i] = bf16( W[kb*8+i][(c>>2)*1024 + 4b + (c&3)] )
// grid = (256 colgroups, 8 pieces), 256 threads.
// ---------------------------------------------------------------------------
struct PackArgs { const float* src[8]; };

__global__ void pack_all(PackArgs pa, ushort* __restrict__ dst) {
  __shared__ ushort tile[1024 * 16];              // [k][c], 32 KB
  const int piece = blockIdx.y;
  const int K = (piece == 7) ? 512 : 1024;
  const float* __restrict__ src = pa.src[piece];
  const int b = blockIdx.x, tid = threadIdx.x;
  for (int idx = tid; idx < K * 4; idx += 256) {
    int k = idx >> 2, g = idx & 3;
    float4 v = *reinterpret_cast<const float4*>(src + (size_t)k * 4096 + g * 1024 + 4 * b);
    ushort* tp = &tile[k * 16 + g * 4];
    tp[0] = f2bf(v.x); tp[1] = f2bf(v.y); tp[2] = f2bf(v.z); tp[3] = f2bf(v.w);
  }
  __syncthreads();
  ushort* db = dst + (size_t)piece * PIECE_ELEMS + (size_t)b * K * 16;
  for (int o8 = tid; o8 < K * 2; o8 += 256) {
    int kb = o8 >> 4, c = o8 & 15;
    bf16x8 val;
#pragma unroll
    for (int i = 0; i < 8; ++i) val[i] = (short)tile[(kb * 8 + i) * 16 + c];
    *reinterpret_cast<bf16x8*>(db + (size_t)o8 * 8) = val;  // coalesced
  }
}

// x fp32 -> bf16 (whole [T][64][512] tensor). grid 8192 x 256, exact.
__global__ void cvt_x(const float* __restrict__ x, ushort* __restrict__ xb) {
  int i = blockIdx.x * blockDim.x + threadIdx.x;
  float4 v = reinterpret_cast<const float4*>(x)[i];
  ushort4 u;
  u.x = f2bf(v.x); u.y = f2bf(v.y); u.z = f2bf(v.z); u.w = f2bf(v.w);
  reinterpret_cast<ushort4*>(xb)[i] = u;
}

// ---------------------------------------------------------------------------
// Dual-colgroup GEMM piece: acc[2][64x16] += A[64xK] * W[Kx32]; wave handles
// its K/8 slice. A-fragments shared across both column groups (halves h reads).
// Wb points at this block's g2=0 slice; g2=1 slice is +K*16 elems.
// ---------------------------------------------------------------------------
template <int K>
DEVINL void gemm2(f32x4 (&acc)[2][4], const ushort* __restrict__ A, int lda,
                  const ushort* __restrict__ Wb, int w, int r16, int q) {
  const int kw = (K / 8) * w;                     // wave's k-range start
  const ushort* wp = Wb + (size_t)q * 128 + (size_t)r16 * 8;
  const ushort* ap = A + r16 * lda + q * 8;
#pragma unroll
  for (int ks = 0; ks < K / 256; ++ks) {
    const int k0 = kw + ks * 32;
    const size_t wo = (size_t)(k0 >> 3) * 128;
    bf16x8 bf0 = __builtin_nontemporal_load(reinterpret_cast<const bf16x8*>(wp + wo));
    bf16x8 bf1 = __builtin_nontemporal_load(reinterpret_cast<const bf16x8*>(wp + wo + (size_t)K * 16));
    bf16x8 a0 = *reinterpret_cast<const bf16x8*>(ap + 0 * 16 * lda + k0);
    bf16x8 a1 = *reinterpret_cast<const bf16x8*>(ap + 1 * 16 * lda + k0);
    bf16x8 a2 = *reinterpret_cast<const bf16x8*>(ap + 2 * 16 * lda + k0);
    bf16x8 a3 = *reinterpret_cast<const bf16x8*>(ap + 3 * 16 * lda + k0);
    acc[0][0] = __builtin_amdgcn_mfma_f32_16x16x32_bf16(a0, bf0, acc[0][0], 0, 0, 0);
    acc[0][1] = __builtin_amdgcn_mfma_f32_16x16x32_bf16(a1, bf0, acc[0][1], 0, 0, 0);
    acc[0][2] = __builtin_amdgcn_mfma_f32_16x16x32_bf16(a2, bf0, acc[0][2], 0, 0, 0);
    acc[0][3] = __builtin_amdgcn_mfma_f32_16x16x32_bf16(a3, bf0, acc[0][3], 0, 0, 0);
    acc[1][0] = __builtin_amdgcn_mfma_f32_16x16x32_bf16(a0, bf1, acc[1][0], 0, 0, 0);
    acc[1][1] = __builtin_amdgcn_mfma_f32_16x16x32_bf16(a1, bf1, acc[1][1], 0, 0, 0);
    acc[1][2] = __builtin_amdgcn_mfma_f32_16x16x32_bf16(a2, bf1, acc[1][2], 0, 0, 0);
    acc[1][3] = __builtin_amdgcn_mfma_f32_16x16x32_bf16(a3, bf1, acc[1][3], 0, 0, 0);
  }
}

// Grid barrier: 8 groups x 16 blocks, fresh counter per instance. Release
// fence drains producer stores; acquire fence invalidates L1/L2 for consumers.
DEVINL void grid_barrier(int* __restrict__ syncp, int bar) {
  __builtin_amdgcn_fence(__ATOMIC_RELEASE, "agent");
  __syncthreads();
  int* base = syncp + (size_t)bar * 128;          // 8 groups x 16 ints (64B apart)
  if (threadIdx.x == 0)
    __hip_atomic_fetch_add(base + (blockIdx.x & 7) * 16, 1,
                           __ATOMIC_RELAXED, __HIP_MEMORY_SCOPE_AGENT);
  if (threadIdx.x < 8) {
    while (__hip_atomic_load(base + threadIdx.x * 16,
                             __ATOMIC_RELAXED, __HIP_MEMORY_SCOPE_AGENT) < (NBLK / 8))
      __builtin_amdgcn_s_sleep(2);
  }
  __syncthreads();
  __builtin_amdgcn_fence(__ATOMIC_ACQUIRE, "agent");
}

// ---------------------------------------------------------------------------
// Persistent kernel.
// ---------------------------------------------------------------------------
__global__ void __launch_bounds__(512, 2)
lstm_persist(const ushort* __restrict__ Wp, const ushort* __restrict__ xb,
             ushort* __restrict__ Hb, int* __restrict__ syncp, float* __restrict__ outp,
             const float* __restrict__ h0, const float* __restrict__ c0,
             const int* __restrict__ len,
             const float* __restrict__ b0v, const float* __restrict__ b1v,
             const float* __restrict__ b2v) {
  const int pb = blockIdx.x, tid = threadIdx.x;
  const int w = tid >> 6, lane = tid & 63, r16 = lane & 15, q = lane >> 4;
  const int gr = tid >> 3, gj = tid & 7, g2g = gj >> 2, j4 = gj & 3;
  const int gcol = pb * 8 + g2g * 4 + j4;         // this thread's h-column
  __shared__ float zp[8][2][64][17];              // split-K partials, 69.6 KB (pad 17)

  // Per-thread state: one (row, col) of h/c for all 3 layers, gate biases.
  int   mylen = len[gr];
  float h0r = h0[(0 * 64 + gr) * 1024 + gcol], c0r = c0[(0 * 64 + gr) * 1024 + gcol];
  float h1r = h0[(1 * 64 + gr) * 1024 + gcol], c1r = c0[(1 * 64 + gr) * 1024 + gcol];
  float h2r = h0[(2 * 64 + gr) * 1024 + gcol], c2r = c0[(2 * 64 + gr) * 1024 + gcol];
  float bb0[4], bb1[4], bb2[4];
#pragma unroll
  for (int g = 0; g < 4; ++g) {
    bb0[g] = b0v[g * 1024 + gcol];
    bb1[g] = b1v[g * 1024 + gcol];
    bb2[g] = b2v[g * 1024 + gcol];
  }

  // Init ring slot 2 = state at t=-1 (also serves h2(t-2) for t=1).
  {
    ushort* hs = Hb + 2 * HSLOT;
    hs[(0 * 64 + gr) * 1024 + gcol] = f2bf(h0r);
    hs[(1 * 64 + gr) * 1024 + gcol] = f2bf(h1r);
    hs[(2 * 64 + gr) * 1024 + gcol] = f2bf(h2r);
  }
  grid_barrier(syncp, 0);

  const ushort* Wp0 = Wp + 0 * PIECE_ELEMS;       // Whh0   A=h0(t-1)
  const ushort* Wp1 = Wp + 1 * PIECE_ELEMS;       // Wth0   A=h1(t-1)
  const ushort* Wp2 = Wp + 2 * PIECE_ELEMS;       // Whh1   A=h1(t-1)
  const ushort* Wp3 = Wp + 3 * PIECE_ELEMS;       // Wbh1   A=h0(t)
  const ushort* Wp4 = Wp + 4 * PIECE_ELEMS;       // Wth1   A=h2(t-1)
  const ushort* Wp5 = Wp + 5 * PIECE_ELEMS;       // Whh2   A=h2(t-2)
  const ushort* Wp6 = Wp + 6 * PIECE_ELEMS;       // Wih2   A=h1(t-1)
  const ushort* Wp7 = Wp + 7 * PIECE_ELEMS;       // Wbh0   A=x_t (K=512)
  const size_t wb1024 = (size_t)(2 * pb) * 1024 * 16;  // block's g2=0 slice offset
  const size_t wb512  = (size_t)(2 * pb) * 512 * 16;

  // Split-K reduce + gates + masked update + bf16 mirror (+ optional fp32 out).
  auto do_cell = [&](f32x4 (&acc)[2][4], const float* bb, float& hr, float& cr,
                     ushort* hbw, bool upd, float* ow) {
#pragma unroll
    for (int g2 = 0; g2 < 2; ++g2)
#pragma unroll
      for (int mf = 0; mf < 4; ++mf)
#pragma unroll
        for (int rg = 0; rg < 4; ++rg)
          zp[w][g2][mf * 16 + q * 4 + rg][r16] = acc[g2][mf][rg];
    __syncthreads();
    float z0 = bb[0], z1 = bb[1], z2 = bb[2], z3 = bb[3];
#pragma unroll
    for (int ww = 0; ww < 8; ++ww) {
      const float* zr = &zp[ww][g2g][gr][j4];
      z0 += zr[0]; z1 += zr[4]; z2 += zr[8]; z3 += zr[12];
    }
    float fg = sigf(z0), ig = sigf(z1), og = sigf(z2), gg = tanhf_(z3);
    float cn = fg * cr + ig * gg;
    float hn = og * tanhf_(cn);
    if (upd) { cr = cn; hr = hn; }                // freeze when t >= length
    hbw[gr * 1024 + gcol] = f2bf(hr);
    if (ow) ow[gr * 1024 + gcol] = hr;
    __syncthreads();                              // zp reused by next cell
  };

  for (int t = 0; t < T_; ++t) {
    const int sC  = t % 3;                        // slot(t)
    const int sP  = (t + 2) % 3;                  // slot(t-1)
    const int sPP = (t + 1) % 3;                  // slot(t-2)
    ushort* HS_C        = Hb + (size_t)sC * HSLOT;
    const ushort* HS_P  = Hb + (size_t)sP * HSLOT;
    const ushort* HS_PP = Hb + (size_t)sPP * HSLOT;

    { // ---- phase A: cell0(t) + cell2(t-1) ---------------------------------
      f32x4 a0[2][4] = {{{0,0,0,0},{0,0,0,0},{0,0,0,0},{0,0,0,0}},
                        {{0,0,0,0},{0,0,0,0},{0,0,0,0},{0,0,0,0}}};
      f32x4 a2[2][4] = {{{0,0,0,0},{0,0,0,0},{0,0,0,0},{0,0,0,0}},
                        {{0,0,0,0},{0,0,0,0},{0,0,0,0},{0,0,0,0}}};
      gemm2<1024>(a0, HS_P + 0 * 65536, 1024, Wp0 + wb1024, w, r16, q);
      gemm2<1024>(a0, HS_P + 1 * 65536, 1024, Wp1 + wb1024, w, r16, q);
      gemm2<512 >(a0, xb + (size_t)t * 32768, 512, Wp7 + wb512, w, r16, q);
      if (t > 0) {
        gemm2<1024>(a2, HS_PP + 2 * 65536, 1024, Wp5 + wb1024, w, r16, q);
        gemm2<1024>(a2, HS_P  + 1 * 65536, 1024, Wp6 + wb1024, w, r16, q);
      }
      do_cell(a0, bb0, h0r, c0r, HS_C + 0 * 65536, t < mylen, nullptr);
      if (t > 0)
        do_cell(a2, bb2, h2r, c2r, Hb + (size_t)sP * HSLOT + 2 * 65536,
                (t - 1) < mylen, outp + (size_t)(t - 1) * 65536);
      grid_barrier(syncp, 1 + 2 * t);
    }
    { // ---- phase B: cell1(t) ----------------------------------------------
      f32x4 a1[2][4] = {{{0,0,0,0},{0,0,0,0},{0,0,0,0},{0,0,0,0}},
                        {{0,0,0,0},{0,0,0,0},{0,0,0,0},{0,0,0,0}}};
      gemm2<1024>(a1, HS_P + 1 * 65536, 1024, Wp2 + wb1024, w, r16, q);
      gemm2<1024>(a1, HS_C + 0 * 65536, 1024, Wp3 + wb1024, w, r16, q);
      gemm2<1024>(a1, HS_P + 2 * 65536, 1024, Wp4 + wb1024, w, r16, q);
      do_cell(a1, bb1, h1r, c1r, HS_C + 1 * 65536, t < mylen, nullptr);
      grid_barrier(syncp, 2 + 2 * t);
    }
  }

  { // ---- epilogue: cell2(T-1) ---------------------------------------------
    const int t = T_;                             // 256
    const int sP = (t + 2) % 3, sPP = (t + 1) % 3;
    f32x4 a2[2][4] = {{{0,0,0,0},{0,0,0,0},{0,0,0,0},{0,0,0,0}},
                      {{0,0,0,0},{0,0,0,0},{0,0,0,0},{0,0,0,0}}};
    gemm2<1024>(a2, Hb + (size_t)sPP * HSLOT + 2 * 65536, 1024, Wp5 + wb1024, w, r16, q);
    gemm2<1024>(a2, Hb + (size_t)sP  * HSLOT + 1 * 65536, 1024, Wp6 + wb1024, w, r16, q);
    do_cell(a2, bb2, h2r, c2r, Hb + (size_t)sP * HSLOT + 2 * 65536,
            (t - 1) < mylen, outp + (size_t)(t - 1) * 65536);
  }

  { // final Ht, C (fp32 from regs)
    float* HtO = outp + (size_t)T_ * 65536;
    float* CO  = HtO + 3 * 65536;
    HtO[(0 * 64 + gr) * 1024 + gcol] = h0r;
    HtO[(1 * 64 + gr) * 1024 + gcol] = h1r;
    HtO[(2 * 64 + gr) * 1024 + gcol] = h2r;
    CO[(0 * 64 + gr) * 1024 + gcol] = c0r;
    CO[(1 * 64 + gr) * 1024 + gcol] = c1r;
    CO[(2 * 64 + gr) * 1024 + gcol] = c2r;
  }
}

// ---------------------------------------------------------------------------
extern "C" void kernel_launch(void* const* d_in, const int* in_sizes, int n_in,
                              void* d_out, int out_size, void* d_ws, size_t ws_size,
                              hipStream_t stream) {
  (void)in_sizes; (void)n_in; (void)out_size; (void)ws_size;
  const float* x    = (const float*)d_in[0];
  const int*   len  = (const int*)d_in[1];
  const float* h0   = (const float*)d_in[2];
  const float* c0   = (const float*)d_in[3];
  const float* Wbh0 = (const float*)d_in[4];
  const float* Whh0 = (const float*)d_in[5];
  const float* Wth0 = (const float*)d_in[6];
  const float* b0   = (const float*)d_in[7];
  const float* Wbh1 = (const float*)d_in[8];
  const float* Whh1 = (const float*)d_in[9];
  const float* Wth1 = (const float*)d_in[10];
  const float* b1   = (const float*)d_in[11];
  const float* Wih2 = (const float*)d_in[12];
  const float* Whh2 = (const float*)d_in[13];
  const float* b2   = (const float*)d_in[14];

  ushort* Wp    = (ushort*)d_ws;
  ushort* xb    = (ushort*)((char*)d_ws + XB_OFF_B);
  ushort* Hb    = (ushort*)((char*)d_ws + HB_OFF_B);
  int*    syncp = (int*)((char*)d_ws + SYNC_OFF_B);

  PackArgs pa;
  pa.src[0] = Whh0; pa.src[1] = Wth0; pa.src[2] = Whh1; pa.src[3] = Wbh1;
  pa.src[4] = Wth1; pa.src[5] = Whh2; pa.src[6] = Wih2; pa.src[7] = Wbh0;
  pack_all<<<dim3(256, 8), 256, 0, stream>>>(pa, Wp);
  cvt_x<<<8192, 256, 0, stream>>>(x, xb);
  (void)hipMemsetAsync(syncp, 0, SYNC_BYTES, stream);

  lstm_persist<<<NBLK, 512, 0, stream>>>(Wp, xb, Hb, syncp, (float*)d_out,
                                         h0, c0, len, b0, b1, b2);
}